// Round 14
// baseline (67.559 us; speedup 1.0000x reference)
//
#include <hip/hip_runtime.h>
#include <hip/hip_bf16.h>

#define BATCH 8
#define NC    64      // channels (Cin == Cout == 64)
#define HH    32
#define WW    64
#define NN    2048    // HH*WW
#define NCP   72      // padded ci slots per LDS row (conv)
#define NCHUNK 4      // attention j-split factor
#define KVBLK 64      // attention j-tile width

typedef __attribute__((ext_vector_type(8))) short bf16x8;
typedef __attribute__((ext_vector_type(4))) short short4v;
typedef __attribute__((ext_vector_type(4))) float f32x4;

__device__ __forceinline__ unsigned short f2bf(float f) {
    union { float f; unsigned u; } v; v.f = f;
    unsigned r = v.u + 0x7fffu + ((v.u >> 16) & 1u);   // RNE
    return (unsigned short)(r >> 16);
}
__device__ __forceinline__ float bf2f(unsigned short h) {
    union { unsigned u; float f; } v; v.u = ((unsigned)h) << 16;
    return v.f;
}

// slot j (0..63) -> original index (K-dim permutation; same map on both
// operands of every MFMA, so dot products are unchanged).
__device__ __forceinline__ int ci_of_slot(int j) {
    return (j & 32) | (((j >> 2) & 1) << 4) | (((j >> 3) & 3) << 2) | (j & 3);
}
// inverse map for 4-aligned quads: c (e0=0) -> slot base
__device__ __forceinline__ int slot_of_quad(int c) {
    return (c & 32) | ((c & 12) << 1) | ((c & 16) >> 2);
}

// ---------------------------------------------------------------------------
// prep_wx: fused weight+input prep (one launch). UNCHANGED from round 13.
// ---------------------------------------------------------------------------
__global__ __launch_bounds__(256) void prep_wx(
    const float* __restrict__ wq, const float* __restrict__ wk,
    const float* __restrict__ wv, const float* __restrict__ x,
    unsigned short* __restrict__ wb, unsigned short* __restrict__ xb)
{
    __shared__ unsigned short T[32][72];   // [xx][ci] (prep_x part only)
    const int bid = blockIdx.x;
    const int tid = threadIdx.x;

    if (bid < 432) {
        const int idx = bid * 256 + tid;
        if (idx >= 9 * 192 * 64) return;
        const int j    = idx & 63;
        const int row  = (idx >> 6) % 192;
        const int tap  = idx / (192 * 64);
        const int ci   = ci_of_slot(j);
        const int conv = row >> 6;
        const int cout = row & 63;
        const float* ww = (conv == 0) ? wq : (conv == 1) ? wk : wv;
        wb[idx] = f2bf(ww[((size_t)cout * 64 + ci) * 9 + tap]);
        return;
    }

    const int bid2 = bid - 432;            // 0..511
    const int bi   = bid2 >> 6;
    const int rem  = bid2 & 63;
    const int y    = rem >> 1;
    const int x0   = (rem & 1) * 32;

#pragma unroll
    for (int pass = 0; pass < 8; ++pass) {
        const int idx = pass * 256 + tid;          // 2048 elements
        const int ci = idx >> 5, xx0 = idx & 31;
        T[xx0][ci] = f2bf(x[(((size_t)bi * 64 + ci) * 32 + y) * 64 + x0 + xx0]);
    }
    __syncthreads();

    {
        const int xx0 = tid >> 3, j8 = tid & 7;    // 256 uint4 chunks
        unsigned short h[8];
#pragma unroll
        for (int e = 0; e < 8; ++e)
            h[e] = T[xx0][ci_of_slot(j8 * 8 + e)];
        uint4 u;
        u.x = (unsigned)h[0] | ((unsigned)h[1] << 16);
        u.y = (unsigned)h[2] | ((unsigned)h[3] << 16);
        u.z = (unsigned)h[4] | ((unsigned)h[5] << 16);
        u.w = (unsigned)h[6] | ((unsigned)h[7] << 16);
        *(uint4*)(xb + ((((size_t)bi * 32 + y) * 64 + x0 + xx0) * 64) + j8 * 8) = u;
    }
}

// ---------------------------------------------------------------------------
// conv_mfma: implicit-GEMM conv, ct-outer REGISTER-W variant.
// Block = (b, y, x-half, M-half): 96 M-rows x 32 px. ONLY X is in LDS
// (14.7 KB -> grid 1024 fully co-resident, 4 blocks/CU). Per ct (3 output
// tiles/wave): batch-load 18 W fragments (9 taps x 2) straight from
// L2-resident wb into registers, then 18 MFMAs against LDS X frags.
// ZERO in-loop barriers, no W LDS round-trip.
// ---------------------------------------------------------------------------
__global__ __launch_bounds__(256) void conv_mfma(
    const unsigned short* __restrict__ xb,   // [b][y][xx][slot]
    const unsigned short* __restrict__ wb,   // [tap][row][slot]
    const float* __restrict__ bq, const float* __restrict__ bk,
    const float* __restrict__ bv,
    unsigned short* __restrict__ qT,         // [b][n][slot-c]
    unsigned short* __restrict__ kT,         // [b][n][slot-c]
    unsigned short* __restrict__ vv)         // [b][c][slot-n within 64]
{
    __shared__ __align__(16) unsigned short Xs[3][34][NCP];   // 14.7 KB

    const int bid = blockIdx.x;      // 1024 = bi(8) x y(32) x xh(2) x h(2)
    const int bi  = bid >> 7;
    const int rem = bid & 127;
    const int y   = rem >> 2;
    const int xh  = (rem >> 1) & 1;
    const int h   = rem & 1;         // M half: rows h*96 .. h*96+95
    const int tid = threadIdx.x;
    const int l   = tid & 63;
    const int w   = tid >> 6;
    const int g   = l >> 4;
    const int li  = l & 15;
    const int mq  = w & 1;           // 48-row slab within the 96
    const int pp  = w >> 1;          // 16-px slab within the 32
    const int x0  = xh * 32;

    // ---- stage X tile: rows y-1..y+1, cols x0-1 .. x0+32 (zero halo) ----
#pragma unroll
    for (int pass = 0; pass < 4; ++pass) {
        const int chunk = pass * 256 + tid;          // 816 chunks
        if (chunk < 816) {
            const int r  = chunk / 272;              // 272 = 34*8
            const int cc = chunk % 272;
            const int c  = cc >> 3, ci8 = cc & 7;    // c: 0..33
            const int yy = y + r - 1;
            const int xx = x0 + c - 1;
            uint4 d = {0, 0, 0, 0};
            if (yy >= 0 && yy < HH && xx >= 0 && xx < WW)
                d = *(const uint4*)(xb + ((((size_t)bi * HH + yy) * WW + xx) * 64) + ci8 * 8);
            *(uint4*)&Xs[r][c][ci8 * 8] = d;
        }
    }
    __syncthreads();

    f32x4 acc[3];
#pragma unroll
    for (int ct = 0; ct < 3; ++ct) acc[ct] = (f32x4){0, 0, 0, 0};

    // per-lane W base: row = h*96 + mq*48 + li (+ct*16), slot base g*8
    const unsigned short* wrow = wb + ((size_t)(h * 96 + mq * 48 + li)) * 64 + g * 8;

#pragma unroll
    for (int ct = 0; ct < 3; ++ct) {
        const unsigned short* wct = wrow + ct * (16 * 64);

        // batch-load all 9 taps' W fragments into registers (18 x 16B)
        bf16x8 wf0[9], wf1[9];
#pragma unroll
        for (int tap = 0; tap < 9; ++tap) {
            wf0[tap] = *(const bf16x8*)(wct + (size_t)tap * (192 * 64));
            wf1[tap] = *(const bf16x8*)(wct + (size_t)tap * (192 * 64) + 32);
        }

        // 9-tap MFMA chain; X frags from LDS (2-way bank alias = free)
#pragma unroll
        for (int tap = 0; tap < 9; ++tap) {
            const int ky = tap / 3, kx = tap % 3;
            const int c = pp * 16 + li + kx;   // 0..33
            const bf16x8 xf0 = *(const bf16x8*)&Xs[ky][c][g * 8];
            const bf16x8 xf1 = *(const bf16x8*)&Xs[ky][c][32 + g * 8];
            acc[ct] = __builtin_amdgcn_mfma_f32_16x16x32_bf16(wf0[tap], xf0, acc[ct], 0, 0, 0);
            acc[ct] = __builtin_amdgcn_mfma_f32_16x16x32_bf16(wf1[tap], xf1, acc[ct], 0, 0, 0);
        }
    }

    // ---- epilogue: bias + slot-permuted store (unchanged from r13) ----
    const int n = y * 64 + x0 + pp * 16 + li;
#pragma unroll
    for (int ct = 0; ct < 3; ++ct) {
        const int rowbase = h * 96 + mq * 48 + ct * 16 + 4 * g;
        const int conv  = rowbase >> 6;
        const int cout0 = rowbase & 63;
        const float* bias = (conv == 0) ? bq : (conv == 1) ? bk : bv;
        float v0 = acc[ct][0] + bias[cout0 + 0];
        float v1 = acc[ct][1] + bias[cout0 + 1];
        float v2 = acc[ct][2] + bias[cout0 + 2];
        float v3 = acc[ct][3] + bias[cout0 + 3];
        if (conv < 2) {
            uint2 pk;
            pk.x = (unsigned)f2bf(v0) | ((unsigned)f2bf(v1) << 16);
            pk.y = (unsigned)f2bf(v2) | ((unsigned)f2bf(v3) << 16);
            const int sbase = slot_of_quad(cout0);
            unsigned short* dst = ((conv == 0) ? qT : kT) +
                                  ((size_t)bi * NN + n) * NC + sbase;
            *(uint2*)dst = pk;
        } else {
            const int n64 = x0 + pp * 16 + li;
            const int sv  = slot_of_quad(n64 & ~3) | (n64 & 3);
            const int nv  = y * 64 + sv;
            vv[((size_t)bi * NC + cout0 + 0) * NN + nv] = f2bf(v0);
            vv[((size_t)bi * NC + cout0 + 1) * NN + nv] = f2bf(v1);
            vv[((size_t)bi * NC + cout0 + 2) * NN + nv] = f2bf(v2);
            vv[((size_t)bi * NC + cout0 + 3) * NN + nv] = f2bf(v3);
        }
    }
}

// ---------------------------------------------------------------------------
// attn_mfma_split: UNCHANGED from round 13 (slot-permuted, conflict-free).
// ---------------------------------------------------------------------------
__global__ __launch_bounds__(256) void attn_mfma_split(
    const unsigned short* __restrict__ qT,  // [b][n][slot-c]
    const unsigned short* __restrict__ kT,  // [b][n][slot-c]
    const unsigned short* __restrict__ vv,  // [b][c][slot-n]
    unsigned short* __restrict__ Po,        // [chunk][b][i][slot] bf16
    float* __restrict__ Pm, float* __restrict__ Pl)  // [chunk][b][i]
{
    __shared__ __align__(16) unsigned short Ks[2][KVBLK][72];  // 18.4 KB
    __shared__ __align__(16) unsigned short Vs[2][64][72];     // 18.4 KB

    const int bid  = blockIdx.x;
    const int g8   = bid & 7;
    const int s    = bid >> 3;          // 0..127
    const int qq   = s >> 5;            // 0..3
    const int it   = s & 31;            // i-tile
    const int G    = g8 + 8 * qq;       // 0..31 = 4*bi + chunk
    const int bi   = G >> 2;
    const int chunk= G & 3;

    const int tid = threadIdx.x;
    const int l   = tid & 63;
    const int w   = tid >> 6;
    const int g   = l >> 4;
    const int li  = l & 15;
    const int i0  = it * 64;
    const int jbase = chunk * (NN / NCHUNK);
    const int NT  = (NN / NCHUNK) / KVBLK;    // 8 j-tiles

    const unsigned short* qb = qT + (size_t)bi * NN * NC;
    const unsigned short* kb = kT + (size_t)bi * NN * NC;
    const unsigned short* vb = vv + (size_t)bi * NC * NN;

    // ---- Q fragments straight from global (one-time, contiguous 16B) ----
    const int qrow = i0 + w * 16 + li;
    const bf16x8 qf0 = *(const bf16x8*)(qb + (size_t)qrow * NC + g * 8);
    const bf16x8 qf1 = *(const bf16x8*)(qb + (size_t)qrow * NC + 32 + g * 8);

    // ---- prologue: stage j-tile 0 (K: 64 rows x 64ch, V: 64ch x 64 j) ----
    uint4 kd[2], vd[2];
#pragma unroll
    for (int u = 0; u < 2; ++u) {
        const int chunkid = u * 256 + tid;          // 512 chunks each
        const int r = chunkid >> 3, c8 = chunkid & 7;
        kd[u] = *(const uint4*)(kb + ((size_t)(jbase + r)) * NC + c8 * 8);
        vd[u] = *(const uint4*)(vb + (size_t)r * NN + jbase + c8 * 8);
        *(uint4*)&Ks[0][r][c8 * 8] = kd[u];
        *(uint4*)&Vs[0][r][c8 * 8] = vd[u];
    }
    __syncthreads();

    f32x4 o0 = {0,0,0,0}, o1 = {0,0,0,0}, o2 = {0,0,0,0}, o3 = {0,0,0,0};
    float m = -1e30f, lsum = 0.0f;

    for (int t = 0; t < NT; ++t) {
        const int cur = t & 1;
        if (t < NT - 1) {
            const int j0 = jbase + (t + 1) * KVBLK;
#pragma unroll
            for (int u = 0; u < 2; ++u) {
                const int chunkid = u * 256 + tid;
                const int r = chunkid >> 3, c8 = chunkid & 7;
                kd[u] = *(const uint4*)(kb + ((size_t)(j0 + r)) * NC + c8 * 8);
                vd[u] = *(const uint4*)(vb + (size_t)r * NN + j0 + c8 * 8);
            }
        }

        // ---- QK^T: 4 j-subtiles of 16 rows (contiguous b128 frags) ----
        f32x4 d[4];
        __builtin_amdgcn_s_setprio(1);
#pragma unroll
        for (int jb = 0; jb < 4; ++jb) {
            const bf16x8 kfa = *(const bf16x8*)&Ks[cur][jb * 16 + li][g * 8];
            const bf16x8 kfb = *(const bf16x8*)&Ks[cur][jb * 16 + li][32 + g * 8];
            const f32x4 z = {0,0,0,0};
            d[jb] = __builtin_amdgcn_mfma_f32_16x16x32_bf16(kfa, qf0, z, 0, 0, 0);
            d[jb] = __builtin_amdgcn_mfma_f32_16x16x32_bf16(kfb, qf1, d[jb], 0, 0, 0);
        }
        __builtin_amdgcn_s_setprio(0);

        // ---- online softmax over 16 lane-local scores (row i = li) ----
        float p[16];
#pragma unroll
        for (int jb = 0; jb < 4; ++jb)
#pragma unroll
            for (int e = 0; e < 4; ++e) p[jb * 4 + e] = d[jb][e];

        float pmax = p[0];
#pragma unroll
        for (int e = 1; e < 16; ++e) pmax = fmaxf(pmax, p[e]);
        pmax = fmaxf(pmax, __shfl_xor(pmax, 16));
        pmax = fmaxf(pmax, __shfl_xor(pmax, 32));

        if (!__all(pmax <= m)) {
            const float mn = fmaxf(m, pmax);
            const float alpha = __expf(m - mn);   // ==1 for rows whose max held
            m = mn;
#pragma unroll
            for (int r = 0; r < 4; ++r) {
                const float ar = __shfl(alpha, 4 * g + r, 16);
                o0[r] *= ar; o1[r] *= ar; o2[r] *= ar; o3[r] *= ar;
            }
            lsum *= alpha;
        }

        float ls = 0.0f;
#pragma unroll
        for (int e = 0; e < 16; ++e) {
            p[e] = __expf(p[e] - m);
            ls += p[e];
        }
        ls += __shfl_xor(ls, 16);
        ls += __shfl_xor(ls, 32);
        lsum += ls;

        bf16x8 pf0, pf1;
#pragma unroll
        for (int e = 0; e < 8; ++e) {
            pf0[e] = (short)f2bf(p[e]);
            pf1[e] = (short)f2bf(p[8 + e]);
        }

        // ---- PV: o[cb] += pf0*V[cb][slots 0-31] + pf1*V[cb][slots 32-63] ----
        __builtin_amdgcn_s_setprio(1);
        {
            const bf16x8 va0 = *(const bf16x8*)&Vs[cur][li][g * 8];
            const bf16x8 va1 = *(const bf16x8*)&Vs[cur][li][32 + g * 8];
            o0 = __builtin_amdgcn_mfma_f32_16x16x32_bf16(pf0, va0, o0, 0, 0, 0);
            o0 = __builtin_amdgcn_mfma_f32_16x16x32_bf16(pf1, va1, o0, 0, 0, 0);
            const bf16x8 vb0 = *(const bf16x8*)&Vs[cur][16 + li][g * 8];
            const bf16x8 vb1 = *(const bf16x8*)&Vs[cur][16 + li][32 + g * 8];
            o1 = __builtin_amdgcn_mfma_f32_16x16x32_bf16(pf0, vb0, o1, 0, 0, 0);
            o1 = __builtin_amdgcn_mfma_f32_16x16x32_bf16(pf1, vb1, o1, 0, 0, 0);
            const bf16x8 vc0 = *(const bf16x8*)&Vs[cur][32 + li][g * 8];
            const bf16x8 vc1 = *(const bf16x8*)&Vs[cur][32 + li][32 + g * 8];
            o2 = __builtin_amdgcn_mfma_f32_16x16x32_bf16(pf0, vc0, o2, 0, 0, 0);
            o2 = __builtin_amdgcn_mfma_f32_16x16x32_bf16(pf1, vc1, o2, 0, 0, 0);
            const bf16x8 vd0 = *(const bf16x8*)&Vs[cur][48 + li][g * 8];
            const bf16x8 vd1 = *(const bf16x8*)&Vs[cur][48 + li][32 + g * 8];
            o3 = __builtin_amdgcn_mfma_f32_16x16x32_bf16(pf0, vd0, o3, 0, 0, 0);
            o3 = __builtin_amdgcn_mfma_f32_16x16x32_bf16(pf1, vd1, o3, 0, 0, 0);
        }
        __builtin_amdgcn_s_setprio(0);

        if (t < NT - 1) {
#pragma unroll
            for (int u = 0; u < 2; ++u) {
                const int chunkid = u * 256 + tid;
                const int r = chunkid >> 3, c8 = chunkid & 7;
                *(uint4*)&Ks[cur ^ 1][r][c8 * 8] = kd[u];
                *(uint4*)&Vs[cur ^ 1][r][c8 * 8] = vd[u];
            }
        }
        __syncthreads();
    }

    // ---- store partials, PACKED: row i, slots 4*li..4*li+3 = channels
    //      {li, 16+li, 32+li, 48+li}; combine un-permutes: c = (s&3)*16+(s>>2)
    unsigned short* pob = Po + (((size_t)chunk * BATCH + bi) * NN) * NC;
#pragma unroll
    for (int r = 0; r < 4; ++r) {
        const int row = i0 + w * 16 + 4 * g + r;
        uint2 pk;
        pk.x = (unsigned)f2bf(o0[r]) | ((unsigned)f2bf(o1[r]) << 16);
        pk.y = (unsigned)f2bf(o2[r]) | ((unsigned)f2bf(o3[r]) << 16);
        *(uint2*)(pob + (size_t)row * NC + 4 * li) = pk;
    }
    if (g == 0) {
        const size_t mi = ((size_t)chunk * BATCH + bi) * NN + i0 + w * 16 + li;
        Pm[mi] = m;
        Pl[mi] = lsum;
    }
}

// ---------------------------------------------------------------------------
// attn_combine: UNCHANGED from round 13.
// ---------------------------------------------------------------------------
__global__ __launch_bounds__(256) void attn_combine(
    const unsigned short* __restrict__ Po,
    const float* __restrict__ Pm, const float* __restrict__ Pl,
    float* __restrict__ out)
{
    __shared__ float wf[NCHUNK][16];
    __shared__ float Os[16][66];

    const int bi = blockIdx.x >> 7;
    const int it = blockIdx.x & 127;
    const int i0 = it * 16;
    const int tid = threadIdx.x;

    if (tid < 64) {
        const int ch = tid >> 4, il = tid & 15;
        wf[ch][il] = Pm[((size_t)ch * BATCH + bi) * NN + i0 + il];
    }
    __syncthreads();
    if (tid < 16) {
        float mv[NCHUNK];
        float ms = -1e30f;
#pragma unroll
        for (int ch = 0; ch < NCHUNK; ++ch) {
            mv[ch] = wf[ch][tid];
            ms = fmaxf(ms, mv[ch]);
        }
        float denom = 0.0f;
        float ev[NCHUNK];
#pragma unroll
        for (int ch = 0; ch < NCHUNK; ++ch) {
            ev[ch] = __expf(mv[ch] - ms);
            denom = fmaf(ev[ch], Pl[((size_t)ch * BATCH + bi) * NN + i0 + tid], denom);
        }
        const float inv = 1.0f / denom;
#pragma unroll
        for (int ch = 0; ch < NCHUNK; ++ch)
            wf[ch][tid] = ev[ch] * inv;
    }
    __syncthreads();

    {
        const int rg = tid >> 6, ss = tid & 63;    // 4 row-groups of 4
        const int c = (ss & 3) * 16 + (ss >> 2);
#pragma unroll
        for (int k = 0; k < 4; ++k) {
            const int i = rg * 4 + k;
            float acc = 0.0f;
#pragma unroll
            for (int ch = 0; ch < NCHUNK; ++ch) {
                const float pv = bf2f(Po[(((size_t)ch * BATCH + bi) * NN + i0 + i) * NC + ss]);
                acc = fmaf(wf[ch][i], pv, acc);
            }
            Os[i][c] = acc;
        }
    }
    __syncthreads();

    {
        const int c = tid & 63, rg = tid >> 6;
        float* ob = out + ((size_t)bi * NC + c) * NN + i0 + rg * 4;
        *(float4*)ob = make_float4(Os[rg * 4 + 0][c], Os[rg * 4 + 1][c],
                                   Os[rg * 4 + 2][c], Os[rg * 4 + 3][c]);
    }
}

// ---------------------------------------------------------------------------
extern "C" void kernel_launch(void* const* d_in, const int* in_sizes, int n_in,
                              void* d_out, int out_size, void* d_ws, size_t ws_size,
                              hipStream_t stream)
{
    const float* x  = (const float*)d_in[0];
    const float* wq = (const float*)d_in[1];
    const float* bq = (const float*)d_in[2];
    const float* wk = (const float*)d_in[3];
    const float* bk = (const float*)d_in[4];
    const float* wv = (const float*)d_in[5];
    const float* bv = (const float*)d_in[6];

    unsigned short* ws16 = (unsigned short*)d_ws;
    const size_t TEN = (size_t)BATCH * NN * NC;                 // 1M elems
    unsigned short* qT = ws16;                                  // 2MB
    unsigned short* kT = ws16 + TEN;                            // 2MB
    unsigned short* vv = ws16 + 2 * TEN;                        // 2MB
    unsigned short* xb = ws16 + 3 * TEN;                        // 2MB
    unsigned short* wb = ws16 + 4 * TEN;                        // 216KB (pad to 128K elems)
    unsigned short* Po = ws16 + 4 * TEN + 131072;               // NCHUNK*TEN bf16 = 8MB
    float* Pm = (float*)(ws16 + 4 * TEN + 131072 + (size_t)NCHUNK * TEN); // 256KB
    float* Pl = Pm + (size_t)NCHUNK * BATCH * NN;                          // 256KB
    float* out = (float*)d_out;

    prep_wx<<<dim3(944), 256, 0, stream>>>(wq, wk, wv, x, wb, xb);
    conv_mfma<<<dim3(1024), 256, 0, stream>>>(xb, wb, bq, bk, bv, qT, kT, vv);
    attn_mfma_split<<<dim3(BATCH * 32 * NCHUNK), 256, 0, stream>>>(qT, kT, vv, Po, Pm, Pl);
    attn_combine<<<dim3(BATCH * 128), 256, 0, stream>>>(Po, Pm, Pl, out);
}

// Round 15
// 52.698 us; speedup vs baseline: 1.2820x; 1.2820x over previous
//
#include <hip/hip_runtime.h>
#include <hip/hip_bf16.h>

#define BATCH 8
#define NC    64      // channels (Cin == Cout == 64)
#define HH    32
#define WW    64
#define NN    2048    // HH*WW
#define NCP   72      // padded ci slots per LDS row (conv)
#define NCHUNK 4      // attention j-split factor
#define KVBLK 64      // attention j-tile width

typedef __attribute__((ext_vector_type(8))) short bf16x8;
typedef __attribute__((ext_vector_type(4))) short short4v;
typedef __attribute__((ext_vector_type(4))) float f32x4;

__device__ __forceinline__ unsigned short f2bf(float f) {
    union { float f; unsigned u; } v; v.f = f;
    unsigned r = v.u + 0x7fffu + ((v.u >> 16) & 1u);   // RNE
    return (unsigned short)(r >> 16);
}
__device__ __forceinline__ float bf2f(unsigned short h) {
    union { unsigned u; float f; } v; v.u = ((unsigned)h) << 16;
    return v.f;
}

// slot j (0..63) -> original index (K-dim permutation; same map on both
// operands of every MFMA, so dot products are unchanged).
__device__ __forceinline__ int ci_of_slot(int j) {
    return (j & 32) | (((j >> 2) & 1) << 4) | (((j >> 3) & 3) << 2) | (j & 3);
}
// inverse map for 4-aligned quads: c (e0=0) -> slot base
__device__ __forceinline__ int slot_of_quad(int c) {
    return (c & 32) | ((c & 12) << 1) | ((c & 16) >> 2);
}

// ---------------------------------------------------------------------------
// prep_wx: fused weight+input prep (one launch). Round-13 version.
// ---------------------------------------------------------------------------
__global__ __launch_bounds__(256) void prep_wx(
    const float* __restrict__ wq, const float* __restrict__ wk,
    const float* __restrict__ wv, const float* __restrict__ x,
    unsigned short* __restrict__ wb, unsigned short* __restrict__ xb)
{
    __shared__ unsigned short T[32][72];   // [xx][ci] (prep_x part only)
    const int bid = blockIdx.x;
    const int tid = threadIdx.x;

    if (bid < 432) {
        const int idx = bid * 256 + tid;
        if (idx >= 9 * 192 * 64) return;
        const int j    = idx & 63;
        const int row  = (idx >> 6) % 192;
        const int tap  = idx / (192 * 64);
        const int ci   = ci_of_slot(j);
        const int conv = row >> 6;
        const int cout = row & 63;
        const float* ww = (conv == 0) ? wq : (conv == 1) ? wk : wv;
        wb[idx] = f2bf(ww[((size_t)cout * 64 + ci) * 9 + tap]);
        return;
    }

    const int bid2 = bid - 432;            // 0..511
    const int bi   = bid2 >> 6;
    const int rem  = bid2 & 63;
    const int y    = rem >> 1;
    const int x0   = (rem & 1) * 32;

#pragma unroll
    for (int pass = 0; pass < 8; ++pass) {
        const int idx = pass * 256 + tid;          // 2048 elements
        const int ci = idx >> 5, xx0 = idx & 31;
        T[xx0][ci] = f2bf(x[(((size_t)bi * 64 + ci) * 32 + y) * 64 + x0 + xx0]);
    }
    __syncthreads();

    {
        const int xx0 = tid >> 3, j8 = tid & 7;    // 256 uint4 chunks
        unsigned short h[8];
#pragma unroll
        for (int e = 0; e < 8; ++e)
            h[e] = T[xx0][ci_of_slot(j8 * 8 + e)];
        uint4 u;
        u.x = (unsigned)h[0] | ((unsigned)h[1] << 16);
        u.y = (unsigned)h[2] | ((unsigned)h[3] << 16);
        u.z = (unsigned)h[4] | ((unsigned)h[5] << 16);
        u.w = (unsigned)h[6] | ((unsigned)h[7] << 16);
        *(uint4*)(xb + ((((size_t)bi * 32 + y) * 64 + x0 + xx0) * 64) + j8 * 8) = u;
    }
}

// ---------------------------------------------------------------------------
// conv_mfma: implicit-GEMM conv — EXACT round-13 version (52.7us best).
// Block = (b, y, x-half, M-half): 96 M-rows x 32 px. Xs 14.7 KB + dbuf Ws
// 27 KB -> 3 blocks/CU, grid 1024. One barrier per tap. Slot-permuted
// epilogue stores (attention reads contiguous b128 fragments).
// W stays in LDS: broadcast-reused operands belong in LDS (r7/r14 lesson).
// ---------------------------------------------------------------------------
__global__ __launch_bounds__(256) void conv_mfma(
    const unsigned short* __restrict__ xb,   // [b][y][xx][slot]
    const unsigned short* __restrict__ wb,   // [tap][row][slot]
    const float* __restrict__ bq, const float* __restrict__ bk,
    const float* __restrict__ bv,
    unsigned short* __restrict__ qT,         // [b][n][slot-c]
    unsigned short* __restrict__ kT,         // [b][n][slot-c]
    unsigned short* __restrict__ vv)         // [b][c][slot-n within 64]
{
    __shared__ __align__(16) unsigned short Xs[3][34][NCP];   // 14.7 KB
    __shared__ __align__(16) unsigned short Ws[2][96][NCP];   // 27.0 KB

    const int bid = blockIdx.x;      // 1024 = bi(8) x y(32) x xh(2) x h(2)
    const int bi  = bid >> 7;
    const int rem = bid & 127;
    const int y   = rem >> 2;
    const int xh  = (rem >> 1) & 1;
    const int h   = rem & 1;         // M half: rows h*96 .. h*96+95
    const int tid = threadIdx.x;
    const int l   = tid & 63;
    const int w   = tid >> 6;
    const int g   = l >> 4;
    const int li  = l & 15;
    const int mq  = w & 1;           // 48-row slab within the 96
    const int pp  = w >> 1;          // 16-px slab within the 32
    const int x0  = xh * 32;

    // ---- stage X tile: rows y-1..y+1, cols x0-1 .. x0+32 (zero halo) ----
#pragma unroll
    for (int pass = 0; pass < 4; ++pass) {
        const int chunk = pass * 256 + tid;          // 816 chunks
        if (chunk < 816) {
            const int r  = chunk / 272;              // 272 = 34*8
            const int cc = chunk % 272;
            const int c  = cc >> 3, ci8 = cc & 7;    // c: 0..33
            const int yy = y + r - 1;
            const int xx = x0 + c - 1;
            uint4 d = {0, 0, 0, 0};
            if (yy >= 0 && yy < HH && xx >= 0 && xx < WW)
                d = *(const uint4*)(xb + ((((size_t)bi * HH + yy) * WW + xx) * 64) + ci8 * 8);
            *(uint4*)&Xs[r][c][ci8 * 8] = d;
        }
    }
    // ---- stage W tap 0 into buffer 0 (96 rows -> 768 chunks, 3/thread) ----
#pragma unroll
    for (int pass = 0; pass < 3; ++pass) {
        const int chunk = pass * 256 + tid;
        const int row = chunk >> 3, ci8 = chunk & 7;
        uint4 d = *(const uint4*)(wb + ((size_t)(h * 96 + row)) * 64 + ci8 * 8);
        *(uint4*)&Ws[0][row][ci8 * 8] = d;
    }
    __syncthreads();

    f32x4 acc[3];
#pragma unroll
    for (int ct = 0; ct < 3; ++ct) acc[ct] = (f32x4){0, 0, 0, 0};

#pragma unroll
    for (int tap = 0; tap < 9; ++tap) {
        const int ky = tap / 3, kx = tap % 3;
        const int cur = tap & 1;

        // prefetch next tap's W into regs (overlaps compute)
        uint4 wd[3];
        if (tap < 8) {
#pragma unroll
            for (int pass = 0; pass < 3; ++pass) {
                const int chunk = pass * 256 + tid;
                const int row = chunk >> 3, ci8 = chunk & 7;
                wd[pass] = *(const uint4*)(wb + ((size_t)(tap + 1) * 192 + h * 96 + row) * 64 + ci8 * 8);
            }
        }

        // B fragments: shifted column reads from Xs
        const int c = pp * 16 + li + kx;   // 0..33
        const bf16x8 xf0 = *(const bf16x8*)&Xs[ky][c][g * 8];
        const bf16x8 xf1 = *(const bf16x8*)&Xs[ky][c][32 + g * 8];

        // A fragments + MFMAs
#pragma unroll
        for (int ct = 0; ct < 3; ++ct) {
            const int row = mq * 48 + ct * 16 + li;
            const bf16x8 wf0 = *(const bf16x8*)&Ws[cur][row][g * 8];
            const bf16x8 wf1 = *(const bf16x8*)&Ws[cur][row][32 + g * 8];
            acc[ct] = __builtin_amdgcn_mfma_f32_16x16x32_bf16(wf0, xf0, acc[ct], 0, 0, 0);
            acc[ct] = __builtin_amdgcn_mfma_f32_16x16x32_bf16(wf1, xf1, acc[ct], 0, 0, 0);
        }

        // write prefetched W into the other buffer; one barrier per tap
        if (tap < 8) {
#pragma unroll
            for (int pass = 0; pass < 3; ++pass) {
                const int chunk = pass * 256 + tid;
                const int row = chunk >> 3, ci8 = chunk & 7;
                *(uint4*)&Ws[cur ^ 1][row][ci8 * 8] = wd[pass];
            }
            __syncthreads();
        }
    }

    // ---- epilogue: bias + slot-permuted store ----
    const int n = y * 64 + x0 + pp * 16 + li;
#pragma unroll
    for (int ct = 0; ct < 3; ++ct) {
        const int rowbase = h * 96 + mq * 48 + ct * 16 + 4 * g;
        const int conv  = rowbase >> 6;
        const int cout0 = rowbase & 63;
        const float* bias = (conv == 0) ? bq : (conv == 1) ? bk : bv;
        float v0 = acc[ct][0] + bias[cout0 + 0];
        float v1 = acc[ct][1] + bias[cout0 + 1];
        float v2 = acc[ct][2] + bias[cout0 + 2];
        float v3 = acc[ct][3] + bias[cout0 + 3];
        if (conv < 2) {
            uint2 pk;
            pk.x = (unsigned)f2bf(v0) | ((unsigned)f2bf(v1) << 16);
            pk.y = (unsigned)f2bf(v2) | ((unsigned)f2bf(v3) << 16);
            const int sbase = slot_of_quad(cout0);
            unsigned short* dst = ((conv == 0) ? qT : kT) +
                                  ((size_t)bi * NN + n) * NC + sbase;
            *(uint2*)dst = pk;
        } else {
            const int n64 = x0 + pp * 16 + li;
            const int sv  = slot_of_quad(n64 & ~3) | (n64 & 3);
            const int nv  = y * 64 + sv;
            vv[((size_t)bi * NC + cout0 + 0) * NN + nv] = f2bf(v0);
            vv[((size_t)bi * NC + cout0 + 1) * NN + nv] = f2bf(v1);
            vv[((size_t)bi * NC + cout0 + 2) * NN + nv] = f2bf(v2);
            vv[((size_t)bi * NC + cout0 + 3) * NN + nv] = f2bf(v3);
        }
    }
}

// ---------------------------------------------------------------------------
// attn_mfma_split: UNCHANGED from round 13 (slot-permuted, conflict-free).
// ---------------------------------------------------------------------------
__global__ __launch_bounds__(256) void attn_mfma_split(
    const unsigned short* __restrict__ qT,  // [b][n][slot-c]
    const unsigned short* __restrict__ kT,  // [b][n][slot-c]
    const unsigned short* __restrict__ vv,  // [b][c][slot-n]
    unsigned short* __restrict__ Po,        // [chunk][b][i][slot] bf16
    float* __restrict__ Pm, float* __restrict__ Pl)  // [chunk][b][i]
{
    __shared__ __align__(16) unsigned short Ks[2][KVBLK][72];  // 18.4 KB
    __shared__ __align__(16) unsigned short Vs[2][64][72];     // 18.4 KB

    const int bid  = blockIdx.x;
    const int g8   = bid & 7;
    const int s    = bid >> 3;          // 0..127
    const int qq   = s >> 5;            // 0..3
    const int it   = s & 31;            // i-tile
    const int G    = g8 + 8 * qq;       // 0..31 = 4*bi + chunk
    const int bi   = G >> 2;
    const int chunk= G & 3;

    const int tid = threadIdx.x;
    const int l   = tid & 63;
    const int w   = tid >> 6;
    const int g   = l >> 4;
    const int li  = l & 15;
    const int i0  = it * 64;
    const int jbase = chunk * (NN / NCHUNK);
    const int NT  = (NN / NCHUNK) / KVBLK;    // 8 j-tiles

    const unsigned short* qb = qT + (size_t)bi * NN * NC;
    const unsigned short* kb = kT + (size_t)bi * NN * NC;
    const unsigned short* vb = vv + (size_t)bi * NC * NN;

    // ---- Q fragments straight from global (one-time, contiguous 16B) ----
    const int qrow = i0 + w * 16 + li;
    const bf16x8 qf0 = *(const bf16x8*)(qb + (size_t)qrow * NC + g * 8);
    const bf16x8 qf1 = *(const bf16x8*)(qb + (size_t)qrow * NC + 32 + g * 8);

    // ---- prologue: stage j-tile 0 (K: 64 rows x 64ch, V: 64ch x 64 j) ----
    uint4 kd[2], vd[2];
#pragma unroll
    for (int u = 0; u < 2; ++u) {
        const int chunkid = u * 256 + tid;          // 512 chunks each
        const int r = chunkid >> 3, c8 = chunkid & 7;
        kd[u] = *(const uint4*)(kb + ((size_t)(jbase + r)) * NC + c8 * 8);
        vd[u] = *(const uint4*)(vb + (size_t)r * NN + jbase + c8 * 8);
        *(uint4*)&Ks[0][r][c8 * 8] = kd[u];
        *(uint4*)&Vs[0][r][c8 * 8] = vd[u];
    }
    __syncthreads();

    f32x4 o0 = {0,0,0,0}, o1 = {0,0,0,0}, o2 = {0,0,0,0}, o3 = {0,0,0,0};
    float m = -1e30f, lsum = 0.0f;

    for (int t = 0; t < NT; ++t) {
        const int cur = t & 1;
        if (t < NT - 1) {
            const int j0 = jbase + (t + 1) * KVBLK;
#pragma unroll
            for (int u = 0; u < 2; ++u) {
                const int chunkid = u * 256 + tid;
                const int r = chunkid >> 3, c8 = chunkid & 7;
                kd[u] = *(const uint4*)(kb + ((size_t)(j0 + r)) * NC + c8 * 8);
                vd[u] = *(const uint4*)(vb + (size_t)r * NN + j0 + c8 * 8);
            }
        }

        // ---- QK^T: 4 j-subtiles of 16 rows (contiguous b128 frags) ----
        f32x4 d[4];
        __builtin_amdgcn_s_setprio(1);
#pragma unroll
        for (int jb = 0; jb < 4; ++jb) {
            const bf16x8 kfa = *(const bf16x8*)&Ks[cur][jb * 16 + li][g * 8];
            const bf16x8 kfb = *(const bf16x8*)&Ks[cur][jb * 16 + li][32 + g * 8];
            const f32x4 z = {0,0,0,0};
            d[jb] = __builtin_amdgcn_mfma_f32_16x16x32_bf16(kfa, qf0, z, 0, 0, 0);
            d[jb] = __builtin_amdgcn_mfma_f32_16x16x32_bf16(kfb, qf1, d[jb], 0, 0, 0);
        }
        __builtin_amdgcn_s_setprio(0);

        // ---- online softmax over 16 lane-local scores (row i = li) ----
        float p[16];
#pragma unroll
        for (int jb = 0; jb < 4; ++jb)
#pragma unroll
            for (int e = 0; e < 4; ++e) p[jb * 4 + e] = d[jb][e];

        float pmax = p[0];
#pragma unroll
        for (int e = 1; e < 16; ++e) pmax = fmaxf(pmax, p[e]);
        pmax = fmaxf(pmax, __shfl_xor(pmax, 16));
        pmax = fmaxf(pmax, __shfl_xor(pmax, 32));

        if (!__all(pmax <= m)) {
            const float mn = fmaxf(m, pmax);
            const float alpha = __expf(m - mn);   // ==1 for rows whose max held
            m = mn;
#pragma unroll
            for (int r = 0; r < 4; ++r) {
                const float ar = __shfl(alpha, 4 * g + r, 16);
                o0[r] *= ar; o1[r] *= ar; o2[r] *= ar; o3[r] *= ar;
            }
            lsum *= alpha;
        }

        float ls = 0.0f;
#pragma unroll
        for (int e = 0; e < 16; ++e) {
            p[e] = __expf(p[e] - m);
            ls += p[e];
        }
        ls += __shfl_xor(ls, 16);
        ls += __shfl_xor(ls, 32);
        lsum += ls;

        bf16x8 pf0, pf1;
#pragma unroll
        for (int e = 0; e < 8; ++e) {
            pf0[e] = (short)f2bf(p[e]);
            pf1[e] = (short)f2bf(p[8 + e]);
        }

        // ---- PV: o[cb] += pf0*V[cb][slots 0-31] + pf1*V[cb][slots 32-63] ----
        __builtin_amdgcn_s_setprio(1);
        {
            const bf16x8 va0 = *(const bf16x8*)&Vs[cur][li][g * 8];
            const bf16x8 va1 = *(const bf16x8*)&Vs[cur][li][32 + g * 8];
            o0 = __builtin_amdgcn_mfma_f32_16x16x32_bf16(pf0, va0, o0, 0, 0, 0);
            o0 = __builtin_amdgcn_mfma_f32_16x16x32_bf16(pf1, va1, o0, 0, 0, 0);
            const bf16x8 vb0 = *(const bf16x8*)&Vs[cur][16 + li][g * 8];
            const bf16x8 vb1 = *(const bf16x8*)&Vs[cur][16 + li][32 + g * 8];
            o1 = __builtin_amdgcn_mfma_f32_16x16x32_bf16(pf0, vb0, o1, 0, 0, 0);
            o1 = __builtin_amdgcn_mfma_f32_16x16x32_bf16(pf1, vb1, o1, 0, 0, 0);
            const bf16x8 vc0 = *(const bf16x8*)&Vs[cur][32 + li][g * 8];
            const bf16x8 vc1 = *(const bf16x8*)&Vs[cur][32 + li][32 + g * 8];
            o2 = __builtin_amdgcn_mfma_f32_16x16x32_bf16(pf0, vc0, o2, 0, 0, 0);
            o2 = __builtin_amdgcn_mfma_f32_16x16x32_bf16(pf1, vc1, o2, 0, 0, 0);
            const bf16x8 vd0 = *(const bf16x8*)&Vs[cur][48 + li][g * 8];
            const bf16x8 vd1 = *(const bf16x8*)&Vs[cur][48 + li][32 + g * 8];
            o3 = __builtin_amdgcn_mfma_f32_16x16x32_bf16(pf0, vd0, o3, 0, 0, 0);
            o3 = __builtin_amdgcn_mfma_f32_16x16x32_bf16(pf1, vd1, o3, 0, 0, 0);
        }
        __builtin_amdgcn_s_setprio(0);

        if (t < NT - 1) {
#pragma unroll
            for (int u = 0; u < 2; ++u) {
                const int chunkid = u * 256 + tid;
                const int r = chunkid >> 3, c8 = chunkid & 7;
                *(uint4*)&Ks[cur ^ 1][r][c8 * 8] = kd[u];
                *(uint4*)&Vs[cur ^ 1][r][c8 * 8] = vd[u];
            }
        }
        __syncthreads();
    }

    // ---- store partials, PACKED: row i, slots 4*li..4*li+3 = channels
    //      {li, 16+li, 32+li, 48+li}; combine un-permutes: c = (s&3)*16+(s>>2)
    unsigned short* pob = Po + (((size_t)chunk * BATCH + bi) * NN) * NC;
#pragma unroll
    for (int r = 0; r < 4; ++r) {
        const int row = i0 + w * 16 + 4 * g + r;
        uint2 pk;
        pk.x = (unsigned)f2bf(o0[r]) | ((unsigned)f2bf(o1[r]) << 16);
        pk.y = (unsigned)f2bf(o2[r]) | ((unsigned)f2bf(o3[r]) << 16);
        *(uint2*)(pob + (size_t)row * NC + 4 * li) = pk;
    }
    if (g == 0) {
        const size_t mi = ((size_t)chunk * BATCH + bi) * NN + i0 + w * 16 + li;
        Pm[mi] = m;
        Pl[mi] = lsum;
    }
}

// ---------------------------------------------------------------------------
// attn_combine: UNCHANGED from round 13.
// ---------------------------------------------------------------------------
__global__ __launch_bounds__(256) void attn_combine(
    const unsigned short* __restrict__ Po,
    const float* __restrict__ Pm, const float* __restrict__ Pl,
    float* __restrict__ out)
{
    __shared__ float wf[NCHUNK][16];
    __shared__ float Os[16][66];

    const int bi = blockIdx.x >> 7;
    const int it = blockIdx.x & 127;
    const int i0 = it * 16;
    const int tid = threadIdx.x;

    if (tid < 64) {
        const int ch = tid >> 4, il = tid & 15;
        wf[ch][il] = Pm[((size_t)ch * BATCH + bi) * NN + i0 + il];
    }
    __syncthreads();
    if (tid < 16) {
        float mv[NCHUNK];
        float ms = -1e30f;
#pragma unroll
        for (int ch = 0; ch < NCHUNK; ++ch) {
            mv[ch] = wf[ch][tid];
            ms = fmaxf(ms, mv[ch]);
        }
        float denom = 0.0f;
        float ev[NCHUNK];
#pragma unroll
        for (int ch = 0; ch < NCHUNK; ++ch) {
            ev[ch] = __expf(mv[ch] - ms);
            denom = fmaf(ev[ch], Pl[((size_t)ch * BATCH + bi) * NN + i0 + tid], denom);
        }
        const float inv = 1.0f / denom;
#pragma unroll
        for (int ch = 0; ch < NCHUNK; ++ch)
            wf[ch][tid] = ev[ch] * inv;
    }
    __syncthreads();

    {
        const int rg = tid >> 6, ss = tid & 63;    // 4 row-groups of 4
        const int c = (ss & 3) * 16 + (ss >> 2);
#pragma unroll
        for (int k = 0; k < 4; ++k) {
            const int i = rg * 4 + k;
            float acc = 0.0f;
#pragma unroll
            for (int ch = 0; ch < NCHUNK; ++ch) {
                const float pv = bf2f(Po[(((size_t)ch * BATCH + bi) * NN + i0 + i) * NC + ss]);
                acc = fmaf(wf[ch][i], pv, acc);
            }
            Os[i][c] = acc;
        }
    }
    __syncthreads();

    {
        const int c = tid & 63, rg = tid >> 6;
        float* ob = out + ((size_t)bi * NC + c) * NN + i0 + rg * 4;
        *(float4*)ob = make_float4(Os[rg * 4 + 0][c], Os[rg * 4 + 1][c],
                                   Os[rg * 4 + 2][c], Os[rg * 4 + 3][c]);
    }
}

// ---------------------------------------------------------------------------
extern "C" void kernel_launch(void* const* d_in, const int* in_sizes, int n_in,
                              void* d_out, int out_size, void* d_ws, size_t ws_size,
                              hipStream_t stream)
{
    const float* x  = (const float*)d_in[0];
    const float* wq = (const float*)d_in[1];
    const float* bq = (const float*)d_in[2];
    const float* wk = (const float*)d_in[3];
    const float* bk = (const float*)d_in[4];
    const float* wv = (const float*)d_in[5];
    const float* bv = (const float*)d_in[6];

    unsigned short* ws16 = (unsigned short*)d_ws;
    const size_t TEN = (size_t)BATCH * NN * NC;                 // 1M elems
    unsigned short* qT = ws16;                                  // 2MB
    unsigned short* kT = ws16 + TEN;                            // 2MB
    unsigned short* vv = ws16 + 2 * TEN;                        // 2MB
    unsigned short* xb = ws16 + 3 * TEN;                        // 2MB
    unsigned short* wb = ws16 + 4 * TEN;                        // 216KB (pad to 128K elems)
    unsigned short* Po = ws16 + 4 * TEN + 131072;               // NCHUNK*TEN bf16 = 8MB
    float* Pm = (float*)(ws16 + 4 * TEN + 131072 + (size_t)NCHUNK * TEN); // 256KB
    float* Pl = Pm + (size_t)NCHUNK * BATCH * NN;                          // 256KB
    float* out = (float*)d_out;

    prep_wx<<<dim3(944), 256, 0, stream>>>(wq, wk, wv, x, wb, xb);
    conv_mfma<<<dim3(1024), 256, 0, stream>>>(xb, wb, bq, bk, bv, qT, kT, vv);
    attn_mfma_split<<<dim3(BATCH * 32 * NCHUNK), 256, 0, stream>>>(qT, kT, vv, Po, Pm, Pl);
    attn_combine<<<dim3(BATCH * 128), 256, 0, stream>>>(Po, Pm, Pl, out);
}